// Round 3
// baseline (209.543 us; speedup 1.0000x reference)
//
#include <hip/hip_runtime.h>
#include <hip/hip_bf16.h>
#include <math.h>
#include <stdint.h>

// ---------------------------------------------------------------------------
// MultiSimilarityLoss on MI355X.
//   x: [B=4096, D=1024] fp32 (L2-normalized rows), labels: [B] int32
//   out: scalar fp32 = mean over rows of mined multi-similarity loss
// Pipeline (R4) -- sim matrix is NEVER materialized:
//   K0: memset gmin=0xFF.., gmax=0
//   K1: x fp32 -> bf16
//   K2a: GEMM pass 1 (528 upper-tri 128x128, BK=64 dbuf 2-phase, T2 swizzle)
//        -> per-row min_pos/max_neg stats via shfl + ordered-uint atomics.
//        NO C write.
//   K2b: GEMM pass 2 (identical core, bitwise-identical tiles) -> mined
//        exp partial sums per (row, col-block), each slot written by exactly
//        one block (deterministic, no float atomics). NO C write.
//   K3: per-row: sum 32 partials in fixed order, log1p -> rowbuf
//   K4: reduce rowbuf -> out[0]
// R3 post-mortem: GEMM latency-bound at 10% MfmaUtil; fixing the load side
//   (R2->R3) gained little => the epilogue scatter-store storm + 64MB sim
//   HBM round-trip dominated. MFMA is ~2us/CU => recompute beats materialize.
// ---------------------------------------------------------------------------

#define THRESH    0.5f
#define MARGIN    0.1f
#define SCALE_POS 2.0f
#define SCALE_NEG 40.0f
#define POS_CAP   (1.0f - 1e-5f)

typedef __bf16 bf16x8 __attribute__((ext_vector_type(8)));
typedef float  f32x4  __attribute__((ext_vector_type(4)));

// ---- fp32 -> bf16 (RNE) ----------------------------------------------------
__device__ __forceinline__ uint16_t f2bf(float f) {
  union { float f; uint32_t u; } v; v.f = f;
  uint32_t u = v.u;
  u += 0x7FFFu + ((u >> 16) & 1u);
  return (uint16_t)(u >> 16);
}

// ---- order-preserving float<->uint encode (for atomicMin/Max on floats) ----
__device__ __forceinline__ uint32_t fenc(float f) {
  union { float f; uint32_t u; } v; v.f = f;
  return (v.u & 0x80000000u) ? ~v.u : (v.u ^ 0x80000000u);
}
__device__ __forceinline__ float fdec(uint32_t k) {
  union { float f; uint32_t u; } v;
  v.u = (k & 0x80000000u) ? (k ^ 0x80000000u) : ~k;
  return v.f;
}

__global__ __launch_bounds__(256) void cvt_bf16_kernel(
    const float* __restrict__ x, uint16_t* __restrict__ y, int n) {
  int i = (blockIdx.x * 256 + threadIdx.x) * 4;
  if (i + 3 < n) {
    float4 v = *(const float4*)(x + i);
    ushort4 o;
    o.x = f2bf(v.x); o.y = f2bf(v.y); o.z = f2bf(v.z); o.w = f2bf(v.w);
    *(ushort4*)(y + i) = o;
  }
}

// ---- async global->LDS staging (16B / lane) --------------------------------
#if defined(__has_builtin)
#if __has_builtin(__builtin_amdgcn_global_load_lds)
#define HAVE_GLL 1
#endif
#endif

__device__ __forceinline__ void stage16(const uint16_t* g, uint16_t* lds_wave_base, int lane) {
#ifdef HAVE_GLL
  __builtin_amdgcn_global_load_lds(
      (const __attribute__((address_space(1))) void*)g,
      (__attribute__((address_space(3))) void*)lds_wave_base, 16, 0, 0);
#else
  *(uint4*)(lds_wave_base + lane * 8) = *(const uint4*)g;
#endif
}

// ---- fused GEMM: PASS=1 stats, PASS=2 mined exp partial sums ---------------
template <int PASS>
__global__ __launch_bounds__(256) void simgemm_fused(
    const uint16_t* __restrict__ X, const int* __restrict__ labels,
    uint32_t* __restrict__ gmin, uint32_t* __restrict__ gmax,
    float* __restrict__ psum_part, float* __restrict__ nsum_part,
    int B, int D) {
  // [buf][A=0/B=1][128 rows][64 cols] bf16, 64 KiB
  __shared__ __align__(16) uint16_t sT[2][2][128 * 64];
  __shared__ int slabR[128];
  __shared__ int slabC[128];
  // pass-2 only (allocated both passes; LDS still fits 2 blocks/CU)
  __shared__ float sMinR[128], sMaxR[128], sMinC[128], sMaxC[128];
  __shared__ float psumR[2][128], nsumR[2][128];
  __shared__ float psumC[2][128], nsumC[2][128];

  const int nblk = B >> 7;
  const int nb   = nblk * (nblk + 1) / 2;

  // XCD-aware bijective swizzle (nb % 8 == 0 for B=4096)
  int t = blockIdx.x;
  if ((nb & 7) == 0) {
    const int cpx = nb >> 3;
    t = (t % 8) * cpx + t / 8;
  }
  // triangular decode: t -> (bi, bj), bi <= bj
  int bi = 0;
  while (t >= nblk - bi) { t -= nblk - bi; ++bi; }
  const int bj = bi + t;
  const int bm = bi * 128;
  const int bn = bj * 128;

  const int tid  = threadIdx.x;
  const int wave = tid >> 6;
  const int lane = tid & 63;
  const int waveM = wave >> 1, waveN = wave & 1;

  if (tid < 128) slabR[tid] = labels[bm + tid];
  else           slabC[tid - 128] = labels[bn + tid - 128];

  const uint16_t* gA = X + (size_t)bm * D;
  const uint16_t* gB = X + (size_t)bn * D;

  // staging map: LDS linear 16B-chunk idx = s*256 + tid
  //   row = idx>>3 (128B rows), inverse-swizzled global col byte
  int srcOff[4];
#pragma unroll
  for (int s = 0; s < 4; ++s) {
    const int idx = s * 256 + tid;
    const int row = idx >> 3;
    const int cb  = ((idx & 7) << 4) ^ ((row & 7) << 4);
    srcOff[s] = row * D + (cb >> 1);
  }

  const int fr = lane & 15;
  const int fq = lane >> 4;
  const int sw = (fr & 7) << 4;   // read-side swizzle

  f32x4 acc[4][4] = {};

  const int NT = D >> 6;

  // prologue: stage tile 0 into buf 0
#pragma unroll
  for (int s = 0; s < 4; ++s) {
    uint16_t* dA = &sT[0][0][0] + (s * 256 + wave * 64) * 8;
    uint16_t* dB = &sT[0][1][0] + (s * 256 + wave * 64) * 8;
    stage16(gA + srcOff[s], dA, lane);
    stage16(gB + srcOff[s], dB, lane);
  }
  __syncthreads();

  int cur = 0;
  for (int kt = 0; kt < NT; ++kt) {
    if (kt + 1 < NT) {
      const int k0 = (kt + 1) << 6;
#pragma unroll
      for (int s = 0; s < 4; ++s) {
        uint16_t* dA = &sT[cur ^ 1][0][0] + (s * 256 + wave * 64) * 8;
        uint16_t* dB = &sT[cur ^ 1][1][0] + (s * 256 + wave * 64) * 8;
        stage16(gA + srcOff[s] + k0, dA, lane);
        stage16(gB + srcOff[s] + k0, dB, lane);
      }
    }

    const char* tA = (const char*)&sT[cur][0][0];
    const char* tB = (const char*)&sT[cur][1][0];
#pragma unroll
    for (int kk = 0; kk < 2; ++kk) {
      const int cbyte = (kk * 64 + fq * 16) ^ sw;
      bf16x8 af[4], bfv[4];
#pragma unroll
      for (int mt = 0; mt < 4; ++mt) {
        const int rowa = waveM * 64 + mt * 16 + fr;
        af[mt] = *(const bf16x8*)(tA + rowa * 128 + cbyte);
      }
#pragma unroll
      for (int nt = 0; nt < 4; ++nt) {
        const int rowb = waveN * 64 + nt * 16 + fr;
        bfv[nt] = *(const bf16x8*)(tB + rowb * 128 + cbyte);
      }
#pragma unroll
      for (int mt = 0; mt < 4; ++mt)
#pragma unroll
        for (int nt = 0; nt < 4; ++nt)
          acc[mt][nt] = __builtin_amdgcn_mfma_f32_16x16x32_bf16(
              af[mt], bfv[nt], acc[mt][nt], 0, 0, 0);
    }

    __syncthreads();
    cur ^= 1;
  }

  const float INF = __builtin_inff();

  int lr[4][4];
#pragma unroll
  for (int mt = 0; mt < 4; ++mt)
#pragma unroll
    for (int r = 0; r < 4; ++r)
      lr[mt][r] = slabR[waveM * 64 + mt * 16 + fq * 4 + r];
  int lc[4];
#pragma unroll
  for (int nt = 0; nt < 4; ++nt) lc[nt] = slabC[waveN * 64 + nt * 16 + fr];

  if constexpr (PASS == 1) {
    // ---- per-row stats: min positive (valid), max negative ----------------
    float rmin[4][4], rmax[4][4];
#pragma unroll
    for (int mt = 0; mt < 4; ++mt)
#pragma unroll
      for (int r = 0; r < 4; ++r) { rmin[mt][r] = INF; rmax[mt][r] = -INF; }

#pragma unroll
    for (int mt = 0; mt < 4; ++mt) {
#pragma unroll
      for (int nt = 0; nt < 4; ++nt) {
        const int gcol = bn + waveN * 64 + nt * 16 + fr;
#pragma unroll
        for (int r = 0; r < 4; ++r) {
          const int grow = bm + waveM * 64 + mt * 16 + fq * 4 + r;
          const float s = acc[mt][nt][r];
          if (lr[mt][r] == lc[nt]) {
            if (grow != gcol && s < POS_CAP) rmin[mt][r] = fminf(rmin[mt][r], s);
          } else {
            rmax[mt][r] = fmaxf(rmax[mt][r], s);
          }
        }
      }
    }
#pragma unroll
    for (int mt = 0; mt < 4; ++mt)
#pragma unroll
      for (int r = 0; r < 4; ++r) {
#pragma unroll
        for (int m = 1; m < 16; m <<= 1) {
          rmin[mt][r] = fminf(rmin[mt][r], __shfl_xor(rmin[mt][r], m, 64));
          rmax[mt][r] = fmaxf(rmax[mt][r], __shfl_xor(rmax[mt][r], m, 64));
        }
      }
    if (fr == 0) {
#pragma unroll
      for (int mt = 0; mt < 4; ++mt)
#pragma unroll
        for (int r = 0; r < 4; ++r) {
          const int grow = bm + waveM * 64 + mt * 16 + fq * 4 + r;
          if (rmin[mt][r] < INF)  atomicMin(&gmin[grow], fenc(rmin[mt][r]));
          if (rmax[mt][r] > -INF) atomicMax(&gmax[grow], fenc(rmax[mt][r]));
        }
    }

    // mirrored side
    if (bi != bj) {
      float cmin[4], cmax[4];
#pragma unroll
      for (int nt = 0; nt < 4; ++nt) { cmin[nt] = INF; cmax[nt] = -INF; }
#pragma unroll
      for (int nt = 0; nt < 4; ++nt) {
        const int gcol = bn + waveN * 64 + nt * 16 + fr;
#pragma unroll
        for (int mt = 0; mt < 4; ++mt) {
#pragma unroll
          for (int r = 0; r < 4; ++r) {
            const int grow = bm + waveM * 64 + mt * 16 + fq * 4 + r;
            const float s = acc[mt][nt][r];
            if (lc[nt] == lr[mt][r]) {
              if (grow != gcol && s < POS_CAP) cmin[nt] = fminf(cmin[nt], s);
            } else {
              cmax[nt] = fmaxf(cmax[nt], s);
            }
          }
        }
      }
#pragma unroll
      for (int nt = 0; nt < 4; ++nt) {
#pragma unroll
        for (int m = 16; m < 64; m <<= 1) {
          cmin[nt] = fminf(cmin[nt], __shfl_xor(cmin[nt], m, 64));
          cmax[nt] = fmaxf(cmax[nt], __shfl_xor(cmax[nt], m, 64));
        }
      }
      if (fq == 0) {
#pragma unroll
        for (int nt = 0; nt < 4; ++nt) {
          const int gcol = bn + waveN * 64 + nt * 16 + fr;
          if (cmin[nt] < INF)  atomicMin(&gmin[gcol], fenc(cmin[nt]));
          if (cmax[nt] > -INF) atomicMax(&gmax[gcol], fenc(cmax[nt]));
        }
      }
    }
  } else {
    // ---- PASS 2: mined exp partial sums -----------------------------------
    // decode per-row stats into LDS (both panels)
    if (tid < 128) {
      const uint32_t km = gmin[bm + tid], kx = gmax[bm + tid];
      sMinR[tid] = (km == 0xFFFFFFFFu) ? INF : fdec(km);
      sMaxR[tid] = (kx == 0u) ? -INF : fdec(kx);
    } else {
      const int rr = tid - 128;
      const uint32_t km = gmin[bn + rr], kx = gmax[bn + rr];
      sMinC[rr] = (km == 0xFFFFFFFFu) ? INF : fdec(km);
      sMaxC[rr] = (kx == 0u) ? -INF : fdec(kx);
    }
    __syncthreads();

    const bool offd = (bi != bj);

    float minC[4], maxC[4];
#pragma unroll
    for (int nt = 0; nt < 4; ++nt) {
      const int cloc = waveN * 64 + nt * 16 + fr;
      minC[nt] = sMinC[cloc];
      maxC[nt] = sMaxC[cloc];
    }

    float lp[4][4] = {}, ln_[4][4] = {};
    float lpc[4] = {}, lnc[4] = {};

#pragma unroll
    for (int mt = 0; mt < 4; ++mt) {
#pragma unroll
      for (int r = 0; r < 4; ++r) {
        const int rloc = waveM * 64 + mt * 16 + fq * 4 + r;
        const int grow = bm + rloc;
        const float mR = sMinR[rloc];
        const float xR = sMaxR[rloc];
        const int   la = lr[mt][r];
#pragma unroll
        for (int nt = 0; nt < 4; ++nt) {
          const int gcol = bn + waveN * 64 + nt * 16 + fr;
          const float s = acc[mt][nt][r];
          const bool same = (la == lc[nt]);
          const bool posv = same && (grow != gcol) && (s < POS_CAP);
          const bool negv = !same;
          const float ep = __expf(-SCALE_POS * (s - THRESH));
          const float en = __expf( SCALE_NEG * (s - THRESH));
          if (posv && (s - MARGIN < xR)) lp[mt][r]  += ep;
          if (negv && (s + MARGIN > mR)) ln_[mt][r] += en;
          if (offd) {
            if (posv && (s - MARGIN < maxC[nt])) lpc[nt] += ep;
            if (negv && (s + MARGIN > minC[nt])) lnc[nt] += en;
          }
        }
      }
    }

    // row-side reduce over fr (xor 1..8 stays within 16-lane fq group)
#pragma unroll
    for (int mt = 0; mt < 4; ++mt)
#pragma unroll
      for (int r = 0; r < 4; ++r) {
#pragma unroll
        for (int m = 1; m < 16; m <<= 1) {
          lp[mt][r]  += __shfl_xor(lp[mt][r],  m, 64);
          ln_[mt][r] += __shfl_xor(ln_[mt][r], m, 64);
        }
      }
    if (fr == 0) {
#pragma unroll
      for (int mt = 0; mt < 4; ++mt)
#pragma unroll
        for (int r = 0; r < 4; ++r) {
          const int rloc = waveM * 64 + mt * 16 + fq * 4 + r;
          psumR[waveN][rloc] = lp[mt][r];
          nsumR[waveN][rloc] = ln_[mt][r];
        }
    }

    // col-side reduce over fq (xor 16,32)
    if (offd) {
#pragma unroll
      for (int nt = 0; nt < 4; ++nt) {
#pragma unroll
        for (int m = 16; m < 64; m <<= 1) {
          lpc[nt] += __shfl_xor(lpc[nt], m, 64);
          lnc[nt] += __shfl_xor(lnc[nt], m, 64);
        }
      }
      if (fq == 0) {
#pragma unroll
        for (int nt = 0; nt < 4; ++nt) {
          const int cloc = waveN * 64 + nt * 16 + fr;
          psumC[waveM][cloc] = lpc[nt];
          nsumC[waveM][cloc] = lnc[nt];
        }
      }
    }
    __syncthreads();

    // write partials: each (row, colblock) slot owned by exactly one block
    if (tid < 128) {
      const float p = psumR[0][tid] + psumR[1][tid];
      const float n = nsumR[0][tid] + nsumR[1][tid];
      psum_part[(size_t)(bm + tid) * nblk + bj] = p;
      nsum_part[(size_t)(bm + tid) * nblk + bj] = n;
    } else if (offd) {
      const int rr = tid - 128;
      const float p = psumC[0][rr] + psumC[1][rr];
      const float n = nsumC[0][rr] + nsumC[1][rr];
      psum_part[(size_t)(bn + rr) * nblk + bi] = p;
      nsum_part[(size_t)(bn + rr) * nblk + bi] = n;
    }
  }
}

// ---- per-row final: sum partials (fixed order) + loss ----------------------
__global__ __launch_bounds__(256) void rowfinal_kernel(
    const uint32_t* __restrict__ gmin, const uint32_t* __restrict__ gmax,
    const float* __restrict__ psum_part, const float* __restrict__ nsum_part,
    float* __restrict__ rowbuf, int B, int nblk) {
  const int i = blockIdx.x * 256 + threadIdx.x;
  if (i >= B) return;
  float ps = 0.f, ns = 0.f;
  for (int q = 0; q < nblk; ++q) {
    ps += psum_part[(size_t)i * nblk + q];
    ns += nsum_part[(size_t)i * nblk + q];
  }
  const bool haspos = (gmin[i] != 0xFFFFFFFFu);
  const bool hasneg = (gmax[i] != 0u);
  const bool has_row = haspos && hasneg && (ps > 0.f) && (ns > 0.f);
  rowbuf[i] = has_row
      ? (log1pf(ps) * (1.0f / SCALE_POS) + log1pf(ns) * (1.0f / SCALE_NEG))
      : 0.f;
}

// ---- final reduction: 4096 floats -> out[0] --------------------------------
__global__ __launch_bounds__(256) void finalreduce_kernel(
    const float* __restrict__ rowbuf, float* __restrict__ out, int B) {
  __shared__ float red[4];
  const int tid  = threadIdx.x;
  const int wave = tid >> 6;
  const int lane = tid & 63;

  float s = 0.f;
  for (int j = tid * 4; j < B; j += 1024) {
    float4 v = *(const float4*)(rowbuf + j);
    s += v.x + v.y + v.z + v.w;
  }
#pragma unroll
  for (int m = 32; m > 0; m >>= 1) s += __shfl_xor(s, m, 64);
  if (lane == 0) red[wave] = s;
  __syncthreads();
  if (tid == 0)
    out[0] = (red[0] + red[1] + red[2] + red[3]) * (1.0f / (float)B);
}

// ---------------------------------------------------------------------------
extern "C" void kernel_launch(void* const* d_in, const int* in_sizes, int n_in,
                              void* d_out, int out_size, void* d_ws, size_t ws_size,
                              hipStream_t stream) {
  const float* x      = (const float*)d_in[0];
  const int*   labels = (const int*)d_in[1];
  float*       out    = (float*)d_out;

  const int B = in_sizes[1];           // 4096
  const int D = in_sizes[0] / B;       // 1024
  const int nblk = B / 128;

  char* ws = (char*)d_ws;
  uint16_t* xbf = (uint16_t*)ws;                 ws += (((size_t)B * D * 2) + 255) & ~(size_t)255;
  uint32_t* gmin = (uint32_t*)ws;                ws += (size_t)B * 4;
  uint32_t* gmax = (uint32_t*)ws;                ws += (size_t)B * 4;
  float* psum_part = (float*)ws;                 ws += (size_t)B * nblk * 4;
  float* nsum_part = (float*)ws;                 ws += (size_t)B * nblk * 4;
  float* rowbuf = (float*)ws;                    ws += (size_t)B * 4;

  hipMemsetAsync(gmin, 0xFF, (size_t)B * 4, stream);
  hipMemsetAsync(gmax, 0x00, (size_t)B * 4, stream);

  const int n = B * D;
  cvt_bf16_kernel<<<n / 1024, 256, 0, stream>>>(x, xbf, n);

  const int nb = nblk * (nblk + 1) / 2;   // 528 upper-triangle tiles
  simgemm_fused<1><<<nb, 256, 0, stream>>>(xbf, labels, gmin, gmax,
                                           psum_part, nsum_part, B, D);
  simgemm_fused<2><<<nb, 256, 0, stream>>>(xbf, labels, gmin, gmax,
                                           psum_part, nsum_part, B, D);

  rowfinal_kernel<<<(B + 255) / 256, 256, 0, stream>>>(gmin, gmax, psum_part,
                                                       nsum_part, rowbuf, B, nblk);
  finalreduce_kernel<<<1, 256, 0, stream>>>(rowbuf, out, B);
}